// Round 1
// baseline (3530.106 us; speedup 1.0000x reference)
//
#include <hip/hip_runtime.h>

// STDP IF-neuron network, T=50 sequential steps.
// Shapes: x_seq [T=50, B=256, D=1024] f32, weight [H=2048, D=1024] f32.
// Output: spike_trace [B, H] f32 (integer counts 0..50).
//
// Step t:  mem = x_t @ W^T        [B,H]
//          v += mem; s = (v>=1); v = s?0:v; trace += s
//          W += (0.005/B) * s^T @ x_t     (skipped at t=49: result unused)

#define T_STEPS 50
#define BATCH   256
#define DIM     1024
#define HID     2048
#define LR_OVER_B (0.005f / 256.0f)

#define BK 16

// ---------------- Kernel A: mem = x @ W^T, fused IF update ----------------
// grid (H/64, B/64) = (32, 4), block 256. 4x4 microtile per thread.
__global__ __launch_bounds__(256) void stdp_fwd_if(
    const float* __restrict__ x,   // [B, D] (x_seq + t*B*D)
    const float* __restrict__ w,   // [H, D]
    float* __restrict__ v,         // [B, H]
    float* __restrict__ s,         // [B, H]
    float* __restrict__ trace)     // [B, H] == d_out
{
    __shared__ float as[BK][64];   // x tile, k-major: as[k][b]
    __shared__ float bs[BK][64];   // w tile, k-major: bs[k][h]

    const int tid = threadIdx.x;
    const int tx  = tid & 15;      // h-subtile
    const int ty  = tid >> 4;      // b-subtile
    const int b0  = blockIdx.y * 64;
    const int h0  = blockIdx.x * 64;

    const int row = tid >> 2;        // 0..63 (row within tile for staging)
    const int kq  = (tid & 3) * 4;   // 0,4,8,12 (k offset for staging)

    float acc[4][4] = {};

    for (int k0 = 0; k0 < DIM; k0 += BK) {
        float4 ga = *(const float4*)&x[(size_t)(b0 + row) * DIM + k0 + kq];
        float4 gb = *(const float4*)&w[(size_t)(h0 + row) * DIM + k0 + kq];
        __syncthreads();           // previous iteration's LDS reads done
        as[kq + 0][row] = ga.x; as[kq + 1][row] = ga.y;
        as[kq + 2][row] = ga.z; as[kq + 3][row] = ga.w;
        bs[kq + 0][row] = gb.x; bs[kq + 1][row] = gb.y;
        bs[kq + 2][row] = gb.z; bs[kq + 3][row] = gb.w;
        __syncthreads();
#pragma unroll
        for (int kk = 0; kk < BK; ++kk) {
            float4 af = *(const float4*)&as[kk][ty * 4];
            float4 bf = *(const float4*)&bs[kk][tx * 4];
            float av[4] = {af.x, af.y, af.z, af.w};
            float bv[4] = {bf.x, bf.y, bf.z, bf.w};
#pragma unroll
            for (int m = 0; m < 4; ++m)
#pragma unroll
                for (int n = 0; n < 4; ++n)
                    acc[m][n] = fmaf(av[m], bv[n], acc[m][n]);
        }
    }

    // fused IF neuron update + spike write + trace accumulate
#pragma unroll
    for (int m = 0; m < 4; ++m) {
        size_t idx = (size_t)(b0 + ty * 4 + m) * HID + h0 + tx * 4;
        float4 vv = *(float4*)&v[idx];
        float4 tr = *(float4*)&trace[idx];
        float4 sv;
        float* vvp = &vv.x;
        float* trp = &tr.x;
        float* svp = &sv.x;
#pragma unroll
        for (int n = 0; n < 4; ++n) {
            float nv = vvp[n] + acc[m][n];
            float sp = (nv >= 1.0f) ? 1.0f : 0.0f;
            vvp[n] = (nv >= 1.0f) ? 0.0f : nv;   // hard reset
            svp[n] = sp;
            trp[n] += sp;
        }
        *(float4*)&v[idx]     = vv;
        *(float4*)&s[idx]     = sv;
        *(float4*)&trace[idx] = tr;
    }
}

// ---------------- Kernel B: W += c * s^T @ x ----------------
// grid (D/64, H/64) = (16, 32), block 256. K = B = 256.
__global__ __launch_bounds__(256) void stdp_wupd(
    const float* __restrict__ x,   // [B, D]
    const float* __restrict__ s,   // [B, H]
    float* __restrict__ w)         // [H, D]
{
    __shared__ float ss[BK][64];   // s^T tile: ss[kb][h]
    __shared__ float xs[BK][64];   // x  tile: xs[kb][d]

    const int tid = threadIdx.x;
    const int tx  = tid & 15;      // d-subtile
    const int ty  = tid >> 4;      // h-subtile
    const int h0  = blockIdx.y * 64;
    const int d0  = blockIdx.x * 64;

    const int krow = tid >> 4;       // 0..15 (b within K-tile)
    const int c4   = (tid & 15) * 4; // 0..60 (col within tile)

    float acc[4][4] = {};

    for (int bk0 = 0; bk0 < BATCH; bk0 += BK) {
        float4 gs = *(const float4*)&s[(size_t)(bk0 + krow) * HID + h0 + c4];
        float4 gx = *(const float4*)&x[(size_t)(bk0 + krow) * DIM + d0 + c4];
        __syncthreads();
        *(float4*)&ss[krow][c4] = gs;
        *(float4*)&xs[krow][c4] = gx;
        __syncthreads();
#pragma unroll
        for (int kk = 0; kk < BK; ++kk) {
            float4 af = *(const float4*)&ss[kk][ty * 4];
            float4 bf = *(const float4*)&xs[kk][tx * 4];
            float av[4] = {af.x, af.y, af.z, af.w};
            float bv[4] = {bf.x, bf.y, bf.z, bf.w};
#pragma unroll
            for (int m = 0; m < 4; ++m)
#pragma unroll
                for (int n = 0; n < 4; ++n)
                    acc[m][n] = fmaf(av[m], bv[n], acc[m][n]);
        }
    }

#pragma unroll
    for (int m = 0; m < 4; ++m) {
        size_t idx = (size_t)(h0 + ty * 4 + m) * DIM + d0 + tx * 4;
        float4 wv = *(float4*)&w[idx];
        wv.x = fmaf(LR_OVER_B, acc[m][0], wv.x);
        wv.y = fmaf(LR_OVER_B, acc[m][1], wv.y);
        wv.z = fmaf(LR_OVER_B, acc[m][2], wv.z);
        wv.w = fmaf(LR_OVER_B, acc[m][3], wv.w);
        *(float4*)&w[idx] = wv;
    }
}

extern "C" void kernel_launch(void* const* d_in, const int* in_sizes, int n_in,
                              void* d_out, int out_size, void* d_ws, size_t ws_size,
                              hipStream_t stream) {
    (void)in_sizes; (void)n_in; (void)ws_size;
    const float* x_seq  = (const float*)d_in[0];   // [T, B, D]
    const float* weight = (const float*)d_in[1];   // [H, D]
    float* trace = (float*)d_out;                  // [B, H]

    // workspace layout: W copy | v | s
    float* w = (float*)d_ws;                       // H*D   = 2097152
    float* v = w + (size_t)HID * DIM;              // B*H   = 524288
    float* s = v + (size_t)BATCH * HID;            // B*H   = 524288

    hipMemcpyAsync(w, weight, (size_t)HID * DIM * sizeof(float),
                   hipMemcpyDeviceToDevice, stream);
    hipMemsetAsync(v, 0, (size_t)BATCH * HID * sizeof(float), stream);
    hipMemsetAsync(trace, 0, (size_t)out_size * sizeof(float), stream);

    dim3 blkA(256), grdA(HID / 64, BATCH / 64);    // (32, 4)
    dim3 blkB(256), grdB(DIM / 64, HID / 64);      // (16, 32)

    for (int t = 0; t < T_STEPS; ++t) {
        const float* xt = x_seq + (size_t)t * BATCH * DIM;
        stdp_fwd_if<<<grdA, blkA, 0, stream>>>(xt, w, v, s, trace);
        if (t < T_STEPS - 1) {
            stdp_wupd<<<grdB, blkB, 0, stream>>>(xt, s, w);
        }
    }
}

// Round 2
// 1994.770 us; speedup vs baseline: 1.7697x; 1.7697x over previous
//
#include <hip/hip_runtime.h>
#include <hip/hip_bf16.h>

// STDP IF-neuron network, T=50 sequential steps.
// x_seq [50,256,1024] f32, weight [2048,1024] f32 -> spike_trace [256,2048] f32.
//
// Step t: mem = x_t @ W^T ; v += mem; s = (v>=1); v = s?0:v; trace += s
//         W += (0.005/256) * s^T @ x_t   (skipped at t=49)
//
// Forward GEMM via bf16 MFMA with 2-way split error compensation:
//   x = xh + xl, W = Wh + Wl (bf16 hi + bf16 residual), all 4 cross terms.
//   Residual representation error ~2^-18 relative => ~1e-6 abs in mem,
//   same order as fp32 reorder noise (round-0 fp32 gave absmax 0.0).
// W kept as fp32 master; wupd kernel refreshes Wh/Wl each step.

#define T_STEPS 50
#define BATCH   256
#define DIM     1024
#define HID     2048
#define LR_OVER_B (0.005f / 256.0f)

typedef __attribute__((ext_vector_type(8))) short short8v;
typedef __attribute__((ext_vector_type(4))) float f32x4;

static __device__ __forceinline__ ushort f32_to_bf16u(float f) {
    __hip_bfloat16 h = __float2bfloat16(f);
    return __builtin_bit_cast(unsigned short, h);
}
static __device__ __forceinline__ float bf16u_to_f32(ushort u) {
    __hip_bfloat16 h = __builtin_bit_cast(__hip_bfloat16, u);
    return __bfloat162float(h);
}

// ---------------- prep: split x_seq into bf16 hi/lo ----------------
__global__ __launch_bounds__(256) void split_x_kernel(
    const float* __restrict__ x, ushort* __restrict__ xh,
    ushort* __restrict__ xl, long n4)
{
    long i = (long)blockIdx.x * blockDim.x + threadIdx.x;
    long stride = (long)gridDim.x * blockDim.x;
    for (; i < n4; i += stride) {
        float4 xx = ((const float4*)x)[i];
        ushort4 hi, lo;
        const float* p = &xx.x;
        ushort* hp = &hi.x;
        ushort* lp = &lo.x;
#pragma unroll
        for (int e = 0; e < 4; ++e) {
            ushort h = f32_to_bf16u(p[e]);
            hp[e] = h;
            lp[e] = f32_to_bf16u(p[e] - bf16u_to_f32(h));
        }
        ((ushort4*)xh)[i] = hi;
        ((ushort4*)xl)[i] = lo;
    }
}

// ---------------- prep: copy W to ws + split into bf16 hi/lo ----------------
__global__ __launch_bounds__(256) void split_w_kernel(
    const float* __restrict__ win, float* __restrict__ wout,
    ushort* __restrict__ wh, ushort* __restrict__ wl, long n4)
{
    long i = (long)blockIdx.x * blockDim.x + threadIdx.x;
    long stride = (long)gridDim.x * blockDim.x;
    for (; i < n4; i += stride) {
        float4 ww = ((const float4*)win)[i];
        ((float4*)wout)[i] = ww;
        ushort4 hi, lo;
        const float* p = &ww.x;
        ushort* hp = &hi.x;
        ushort* lp = &lo.x;
#pragma unroll
        for (int e = 0; e < 4; ++e) {
            ushort h = f32_to_bf16u(p[e]);
            hp[e] = h;
            lp[e] = f32_to_bf16u(p[e] - bf16u_to_f32(h));
        }
        ((ushort4*)wh)[i] = hi;
        ((ushort4*)wl)[i] = lo;
    }
}

// ---------------- Kernel A (MFMA): mem = x@W^T with split compensation ----
// Block: 32(b) x 64(h) tile, 128 threads = 2 waves (wave handles 32h half).
// Grid (H/64, B/32) = (32, 8) = 256 blocks.
// LDS tiles padded to stride 72 bf16 (144 B) -> bank-balanced ds_read_b128.
#define PADS 72
__global__ __launch_bounds__(128) void stdp_fwd_mfma(
    const ushort* __restrict__ xh_g,   // [B,D] bf16 (time slice)
    const ushort* __restrict__ xl_g,
    const ushort* __restrict__ wh_g,   // [H,D] bf16
    const ushort* __restrict__ wl_g,
    float* __restrict__ v,             // [B,H]
    float* __restrict__ s,             // [B,H]
    float* __restrict__ trace)         // [B,H] == d_out
{
    __shared__ ushort xhs[32 * PADS];
    __shared__ ushort xls[32 * PADS];
    __shared__ ushort whs[64 * PADS];
    __shared__ ushort wls[64 * PADS];

    const int tid  = threadIdx.x;
    const int lane = tid & 63;
    const int wid  = tid >> 6;            // 0..1: h-half of the block tile
    const int b0   = blockIdx.y * 32;
    const int h0   = blockIdx.x * 64;

    const f32x4 z4 = {0.f, 0.f, 0.f, 0.f};
    f32x4 acc[2][2] = {{z4, z4}, {z4, z4}};   // [b-tile][h-tile]

    for (int k0 = 0; k0 < DIM; k0 += 64) {
        __syncthreads();
        // stage x tiles: 32 rows x 64 k = 256 lane-loads of 16B each
#pragma unroll
        for (int p = 0; p < 2; ++p) {
            int i = p * 128 + tid;
            int r = i >> 3, g = (i & 7) * 8;
            *(short8v*)&xhs[r * PADS + g] =
                *(const short8v*)&xh_g[(size_t)(b0 + r) * DIM + k0 + g];
            *(short8v*)&xls[r * PADS + g] =
                *(const short8v*)&xl_g[(size_t)(b0 + r) * DIM + k0 + g];
        }
        // stage W tiles: 64 rows x 64 k = 512 lane-loads
#pragma unroll
        for (int p = 0; p < 4; ++p) {
            int i = p * 128 + tid;
            int r = i >> 3, g = (i & 7) * 8;
            *(short8v*)&whs[r * PADS + g] =
                *(const short8v*)&wh_g[(size_t)(h0 + r) * DIM + k0 + g];
            *(short8v*)&wls[r * PADS + g] =
                *(const short8v*)&wl_g[(size_t)(h0 + r) * DIM + k0 + g];
        }
        __syncthreads();

#pragma unroll
        for (int kk = 0; kk < 2; ++kk) {
            const int kloc = kk * 32 + (lane >> 4) * 8;
            const int ar = lane & 15;
            // A fragments (x), rows = b-tile
            short8v axh0 = *(const short8v*)&xhs[ar * PADS + kloc];
            short8v axh1 = *(const short8v*)&xhs[(16 + ar) * PADS + kloc];
            short8v axl0 = *(const short8v*)&xls[ar * PADS + kloc];
            short8v axl1 = *(const short8v*)&xls[(16 + ar) * PADS + kloc];
            // B fragments (W rows = output h), this wave's 32-h half
            const int br = wid * 32 + ar;
            short8v bh0 = *(const short8v*)&whs[br * PADS + kloc];
            short8v bh1 = *(const short8v*)&whs[(br + 16) * PADS + kloc];
            short8v bl0 = *(const short8v*)&wls[br * PADS + kloc];
            short8v bl1 = *(const short8v*)&wls[(br + 16) * PADS + kloc];

            acc[0][0] = __builtin_amdgcn_mfma_f32_16x16x32_bf16(axh0, bh0, acc[0][0], 0, 0, 0);
            acc[0][0] = __builtin_amdgcn_mfma_f32_16x16x32_bf16(axh0, bl0, acc[0][0], 0, 0, 0);
            acc[0][0] = __builtin_amdgcn_mfma_f32_16x16x32_bf16(axl0, bh0, acc[0][0], 0, 0, 0);
            acc[0][0] = __builtin_amdgcn_mfma_f32_16x16x32_bf16(axl0, bl0, acc[0][0], 0, 0, 0);

            acc[0][1] = __builtin_amdgcn_mfma_f32_16x16x32_bf16(axh0, bh1, acc[0][1], 0, 0, 0);
            acc[0][1] = __builtin_amdgcn_mfma_f32_16x16x32_bf16(axh0, bl1, acc[0][1], 0, 0, 0);
            acc[0][1] = __builtin_amdgcn_mfma_f32_16x16x32_bf16(axl0, bh1, acc[0][1], 0, 0, 0);
            acc[0][1] = __builtin_amdgcn_mfma_f32_16x16x32_bf16(axl0, bl1, acc[0][1], 0, 0, 0);

            acc[1][0] = __builtin_amdgcn_mfma_f32_16x16x32_bf16(axh1, bh0, acc[1][0], 0, 0, 0);
            acc[1][0] = __builtin_amdgcn_mfma_f32_16x16x32_bf16(axh1, bl0, acc[1][0], 0, 0, 0);
            acc[1][0] = __builtin_amdgcn_mfma_f32_16x16x32_bf16(axl1, bh0, acc[1][0], 0, 0, 0);
            acc[1][0] = __builtin_amdgcn_mfma_f32_16x16x32_bf16(axl1, bl0, acc[1][0], 0, 0, 0);

            acc[1][1] = __builtin_amdgcn_mfma_f32_16x16x32_bf16(axh1, bh1, acc[1][1], 0, 0, 0);
            acc[1][1] = __builtin_amdgcn_mfma_f32_16x16x32_bf16(axh1, bl1, acc[1][1], 0, 0, 0);
            acc[1][1] = __builtin_amdgcn_mfma_f32_16x16x32_bf16(axl1, bh1, acc[1][1], 0, 0, 0);
            acc[1][1] = __builtin_amdgcn_mfma_f32_16x16x32_bf16(axl1, bl1, acc[1][1], 0, 0, 0);
        }
    }

    // fused IF update. C/D layout: col(h)=lane&15, row(b)=(lane>>4)*4+reg.
#pragma unroll
    for (int m = 0; m < 2; ++m) {
#pragma unroll
        for (int n = 0; n < 2; ++n) {
            const int b = b0 + m * 16 + (lane >> 4) * 4;
            const int h = h0 + wid * 32 + n * 16 + (lane & 15);
#pragma unroll
            for (int j = 0; j < 4; ++j) {
                size_t idx = (size_t)(b + j) * HID + h;
                float nv = v[idx] + acc[m][n][j];
                float sp = (nv >= 1.0f) ? 1.0f : 0.0f;
                v[idx] = (nv >= 1.0f) ? 0.0f : nv;
                s[idx] = sp;
                trace[idx] += sp;
            }
        }
    }
}

// ---------------- Kernel B: W += c * s^T @ x, emit bf16 splits -------------
#define BK 16
__global__ __launch_bounds__(256) void stdp_wupd_split(
    const float* __restrict__ x,   // [B, D]
    const float* __restrict__ s,   // [B, H]
    float* __restrict__ w,         // [H, D] fp32 master
    ushort* __restrict__ wh,       // [H, D] bf16 hi
    ushort* __restrict__ wl)       // [H, D] bf16 lo
{
    __shared__ float ss[BK][64];
    __shared__ float xs[BK][64];

    const int tid = threadIdx.x;
    const int tx  = tid & 15;
    const int ty  = tid >> 4;
    const int h0  = blockIdx.y * 64;
    const int d0  = blockIdx.x * 64;

    const int krow = tid >> 4;
    const int c4   = (tid & 15) * 4;

    float acc[4][4] = {};

    for (int bk0 = 0; bk0 < BATCH; bk0 += BK) {
        float4 gs = *(const float4*)&s[(size_t)(bk0 + krow) * HID + h0 + c4];
        float4 gx = *(const float4*)&x[(size_t)(bk0 + krow) * DIM + d0 + c4];
        __syncthreads();
        *(float4*)&ss[krow][c4] = gs;
        *(float4*)&xs[krow][c4] = gx;
        __syncthreads();
#pragma unroll
        for (int kk = 0; kk < BK; ++kk) {
            float4 af = *(const float4*)&ss[kk][ty * 4];
            float4 bf = *(const float4*)&xs[kk][tx * 4];
            float av[4] = {af.x, af.y, af.z, af.w};
            float bv[4] = {bf.x, bf.y, bf.z, bf.w};
#pragma unroll
            for (int m = 0; m < 4; ++m)
#pragma unroll
                for (int n = 0; n < 4; ++n)
                    acc[m][n] = fmaf(av[m], bv[n], acc[m][n]);
        }
    }

#pragma unroll
    for (int m = 0; m < 4; ++m) {
        size_t idx = (size_t)(h0 + ty * 4 + m) * DIM + d0 + tx * 4;
        float4 wv = *(float4*)&w[idx];
        wv.x = fmaf(LR_OVER_B, acc[m][0], wv.x);
        wv.y = fmaf(LR_OVER_B, acc[m][1], wv.y);
        wv.z = fmaf(LR_OVER_B, acc[m][2], wv.z);
        wv.w = fmaf(LR_OVER_B, acc[m][3], wv.w);
        *(float4*)&w[idx] = wv;
        ushort4 hi, lo;
        const float* p = &wv.x;
        ushort* hp = &hi.x;
        ushort* lp = &lo.x;
#pragma unroll
        for (int e = 0; e < 4; ++e) {
            ushort hb = f32_to_bf16u(p[e]);
            hp[e] = hb;
            lp[e] = f32_to_bf16u(p[e] - bf16u_to_f32(hb));
        }
        *(ushort4*)&wh[idx] = hi;
        *(ushort4*)&wl[idx] = lo;
    }
}

// ---------------- fallback fp32 kernels (round-0, ws too small) ------------
__global__ __launch_bounds__(256) void stdp_fwd_if(
    const float* __restrict__ x, const float* __restrict__ w,
    float* __restrict__ v, float* __restrict__ s, float* __restrict__ trace)
{
    __shared__ float as[BK][64];
    __shared__ float bs[BK][64];
    const int tid = threadIdx.x;
    const int tx = tid & 15, ty = tid >> 4;
    const int b0 = blockIdx.y * 64, h0 = blockIdx.x * 64;
    const int row = tid >> 2, kq = (tid & 3) * 4;
    float acc[4][4] = {};
    for (int k0 = 0; k0 < DIM; k0 += BK) {
        float4 ga = *(const float4*)&x[(size_t)(b0 + row) * DIM + k0 + kq];
        float4 gb = *(const float4*)&w[(size_t)(h0 + row) * DIM + k0 + kq];
        __syncthreads();
        as[kq + 0][row] = ga.x; as[kq + 1][row] = ga.y;
        as[kq + 2][row] = ga.z; as[kq + 3][row] = ga.w;
        bs[kq + 0][row] = gb.x; bs[kq + 1][row] = gb.y;
        bs[kq + 2][row] = gb.z; bs[kq + 3][row] = gb.w;
        __syncthreads();
#pragma unroll
        for (int kk = 0; kk < BK; ++kk) {
            float4 af = *(const float4*)&as[kk][ty * 4];
            float4 bf = *(const float4*)&bs[kk][tx * 4];
            float av[4] = {af.x, af.y, af.z, af.w};
            float bv[4] = {bf.x, bf.y, bf.z, bf.w};
#pragma unroll
            for (int m = 0; m < 4; ++m)
#pragma unroll
                for (int n = 0; n < 4; ++n)
                    acc[m][n] = fmaf(av[m], bv[n], acc[m][n]);
        }
    }
#pragma unroll
    for (int m = 0; m < 4; ++m) {
        size_t idx = (size_t)(b0 + ty * 4 + m) * HID + h0 + tx * 4;
        float4 vv = *(float4*)&v[idx];
        float4 tr = *(float4*)&trace[idx];
        float4 sv;
        float* vvp = &vv.x; float* trp = &tr.x; float* svp = &sv.x;
#pragma unroll
        for (int n = 0; n < 4; ++n) {
            float nv = vvp[n] + acc[m][n];
            float sp = (nv >= 1.0f) ? 1.0f : 0.0f;
            vvp[n] = (nv >= 1.0f) ? 0.0f : nv;
            svp[n] = sp; trp[n] += sp;
        }
        *(float4*)&v[idx] = vv;
        *(float4*)&s[idx] = sv;
        *(float4*)&trace[idx] = tr;
    }
}

__global__ __launch_bounds__(256) void stdp_wupd(
    const float* __restrict__ x, const float* __restrict__ s,
    float* __restrict__ w)
{
    __shared__ float ss[BK][64];
    __shared__ float xs[BK][64];
    const int tid = threadIdx.x;
    const int tx = tid & 15, ty = tid >> 4;
    const int h0 = blockIdx.y * 64, d0 = blockIdx.x * 64;
    const int krow = tid >> 4, c4 = (tid & 15) * 4;
    float acc[4][4] = {};
    for (int bk0 = 0; bk0 < BATCH; bk0 += BK) {
        float4 gs = *(const float4*)&s[(size_t)(bk0 + krow) * HID + h0 + c4];
        float4 gx = *(const float4*)&x[(size_t)(bk0 + krow) * DIM + d0 + c4];
        __syncthreads();
        *(float4*)&ss[krow][c4] = gs;
        *(float4*)&xs[krow][c4] = gx;
        __syncthreads();
#pragma unroll
        for (int kk = 0; kk < BK; ++kk) {
            float4 af = *(const float4*)&ss[kk][ty * 4];
            float4 bf = *(const float4*)&xs[kk][tx * 4];
            float av[4] = {af.x, af.y, af.z, af.w};
            float bv[4] = {bf.x, bf.y, bf.z, bf.w};
#pragma unroll
            for (int m = 0; m < 4; ++m)
#pragma unroll
                for (int n = 0; n < 4; ++n)
                    acc[m][n] = fmaf(av[m], bv[n], acc[m][n]);
        }
    }
#pragma unroll
    for (int m = 0; m < 4; ++m) {
        size_t idx = (size_t)(h0 + ty * 4 + m) * DIM + d0 + tx * 4;
        float4 wv = *(float4*)&w[idx];
        wv.x = fmaf(LR_OVER_B, acc[m][0], wv.x);
        wv.y = fmaf(LR_OVER_B, acc[m][1], wv.y);
        wv.z = fmaf(LR_OVER_B, acc[m][2], wv.z);
        wv.w = fmaf(LR_OVER_B, acc[m][3], wv.w);
        *(float4*)&w[idx] = wv;
    }
}

extern "C" void kernel_launch(void* const* d_in, const int* in_sizes, int n_in,
                              void* d_out, int out_size, void* d_ws, size_t ws_size,
                              hipStream_t stream) {
    (void)in_sizes; (void)n_in;
    const float* x_seq  = (const float*)d_in[0];   // [T, B, D]
    const float* weight = (const float*)d_in[1];   // [H, D]
    float* trace = (float*)d_out;                  // [B, H]

    const size_t WN  = (size_t)HID * DIM;          // 2097152
    const size_t BH  = (size_t)BATCH * HID;        // 524288
    const size_t XN  = (size_t)T_STEPS * BATCH * DIM; // 13107200

    // fast-path workspace: W(f32) | v | s | Wh | Wl | xh | xl
    const size_t need = WN * 4 + BH * 4 + BH * 4 + WN * 2 + WN * 2 + XN * 2 + XN * 2;

    if (ws_size >= need) {
        float*  W  = (float*)d_ws;
        float*  v  = W + WN;
        float*  s  = v + BH;
        ushort* Wh = (ushort*)(s + BH);
        ushort* Wl = Wh + WN;
        ushort* xh = Wl + WN;
        ushort* xl = xh + XN;

        split_x_kernel<<<2048, 256, 0, stream>>>(x_seq, xh, xl, (long)(XN / 4));
        split_w_kernel<<<1024, 256, 0, stream>>>(weight, W, Wh, Wl, (long)(WN / 4));
        hipMemsetAsync(v, 0, BH * 4, stream);
        hipMemsetAsync(trace, 0, (size_t)out_size * 4, stream);

        dim3 blkA(128), grdA(HID / 64, BATCH / 32);   // (32, 8) = 256 blocks
        dim3 blkB(256), grdB(DIM / 64, HID / 64);     // (16, 32) = 512 blocks

        for (int t = 0; t < T_STEPS; ++t) {
            const ushort* xht = xh + (size_t)t * BATCH * DIM;
            const ushort* xlt = xl + (size_t)t * BATCH * DIM;
            stdp_fwd_mfma<<<grdA, blkA, 0, stream>>>(xht, xlt, Wh, Wl, v, s, trace);
            if (t < T_STEPS - 1) {
                const float* xt = x_seq + (size_t)t * BATCH * DIM;
                stdp_wupd_split<<<grdB, blkB, 0, stream>>>(xt, s, W, Wh, Wl);
            }
        }
    } else {
        // fallback: round-0 fp32 path (needs 12.6 MB)
        float* w = (float*)d_ws;
        float* v = w + WN;
        float* s = v + BH;
        hipMemcpyAsync(w, weight, WN * 4, hipMemcpyDeviceToDevice, stream);
        hipMemsetAsync(v, 0, BH * 4, stream);
        hipMemsetAsync(trace, 0, (size_t)out_size * 4, stream);
        dim3 blkA(256), grdA(HID / 64, BATCH / 64);
        dim3 blkB(256), grdB(DIM / 64, HID / 64);
        for (int t = 0; t < T_STEPS; ++t) {
            const float* xt = x_seq + (size_t)t * BATCH * DIM;
            stdp_fwd_if<<<grdA, blkA, 0, stream>>>(xt, w, v, s, trace);
            if (t < T_STEPS - 1) {
                stdp_wupd<<<grdB, blkB, 0, stream>>>(xt, s, w);
            }
        }
    }
}

// Round 3
// 1825.432 us; speedup vs baseline: 1.9338x; 1.0928x over previous
//
#include <hip/hip_runtime.h>
#include <hip/hip_bf16.h>

// STDP IF-neuron network, T=50 sequential steps.
// x_seq [50,256,1024] f32, weight [2048,1024] f32 -> spike_trace [256,2048] f32.
//
// Step t: mem = x_t @ W^T ; v += mem; s = (v>=1); v = s?0:v; trace += s
//         W += (0.005/256) * s^T @ x_t   (skipped at t=49)
//
// fwd GEMM: bf16 MFMA, 3-product split compensation (xh*wh + xh*wl + xl*wh;
//   dropped xl*wl ~ 2^-18 rel, same order as split representation error).
// wupd GEMM: bf16 MFMA (s is exactly {0,1} -> exact bf16), K=B=256, using
//   sT [H,B] emitted by fwd and precomputed transposed splits xTh/xTl [T,D,B].
// v and trace kept transposed [H,B] so the IF update is float4-vectorized;
//   final kernel transposes trace -> d_out [B,H].

#define T_STEPS 50
#define BATCH   256
#define DIM     1024
#define HID     2048
#define LR_OVER_B (0.005f / 256.0f)

typedef __attribute__((ext_vector_type(8))) short short8v;
typedef __attribute__((ext_vector_type(4))) float f32x4;

static __device__ __forceinline__ ushort f32_to_bf16u(float f) {
    __hip_bfloat16 h = __float2bfloat16(f);
    return __builtin_bit_cast(unsigned short, h);
}
static __device__ __forceinline__ float bf16u_to_f32(ushort u) {
    __hip_bfloat16 h = __builtin_bit_cast(__hip_bfloat16, u);
    return __bfloat162float(h);
}

// ---------------- prep: split x_seq into bf16 hi/lo (row-major) -----------
__global__ __launch_bounds__(256) void split_x_kernel(
    const float* __restrict__ x, ushort* __restrict__ xh,
    ushort* __restrict__ xl, long n4)
{
    long i = (long)blockIdx.x * blockDim.x + threadIdx.x;
    long stride = (long)gridDim.x * blockDim.x;
    for (; i < n4; i += stride) {
        float4 xx = ((const float4*)x)[i];
        ushort4 hi, lo;
        const float* p = &xx.x;
        ushort* hp = &hi.x;
        ushort* lp = &lo.x;
#pragma unroll
        for (int e = 0; e < 4; ++e) {
            ushort h = f32_to_bf16u(p[e]);
            hp[e] = h;
            lp[e] = f32_to_bf16u(p[e] - bf16u_to_f32(h));
        }
        ((ushort4*)xh)[i] = hi;
        ((ushort4*)xl)[i] = lo;
    }
}

// ---------------- prep: transposed splits xT [T, D, B] --------------------
__global__ __launch_bounds__(256) void transpose_split_x(
    const float* __restrict__ x, ushort* __restrict__ xTh,
    ushort* __restrict__ xTl)
{
    __shared__ float tile[32][33];
    const int t  = blockIdx.z;
    const int d0 = blockIdx.x * 32;
    const int b0 = blockIdx.y * 32;
    const int tx = threadIdx.x & 31;
    const int ty = threadIdx.x >> 5;         // 0..7
    const float* xt = x + (size_t)t * BATCH * DIM;
#pragma unroll
    for (int r = 0; r < 32; r += 8)
        tile[ty + r][tx] = xt[(size_t)(b0 + ty + r) * DIM + d0 + tx];
    __syncthreads();
    ushort* oh = xTh + (size_t)t * DIM * BATCH;
    ushort* ol = xTl + (size_t)t * DIM * BATCH;
#pragma unroll
    for (int r = 0; r < 32; r += 8) {
        float val = tile[tx][ty + r];        // d = d0+ty+r, b = b0+tx
        ushort hi = f32_to_bf16u(val);
        oh[(size_t)(d0 + ty + r) * BATCH + b0 + tx] = hi;
        ol[(size_t)(d0 + ty + r) * BATCH + b0 + tx] =
            f32_to_bf16u(val - bf16u_to_f32(hi));
    }
}

// ---------------- prep: copy W + split into bf16 hi/lo --------------------
__global__ __launch_bounds__(256) void split_w_kernel(
    const float* __restrict__ win, float* __restrict__ wout,
    ushort* __restrict__ wh, ushort* __restrict__ wl, long n4)
{
    long i = (long)blockIdx.x * blockDim.x + threadIdx.x;
    long stride = (long)gridDim.x * blockDim.x;
    for (; i < n4; i += stride) {
        float4 ww = ((const float4*)win)[i];
        ((float4*)wout)[i] = ww;
        ushort4 hi, lo;
        const float* p = &ww.x;
        ushort* hp = &hi.x;
        ushort* lp = &lo.x;
#pragma unroll
        for (int e = 0; e < 4; ++e) {
            ushort h = f32_to_bf16u(p[e]);
            hp[e] = h;
            lp[e] = f32_to_bf16u(p[e] - bf16u_to_f32(h));
        }
        ((ushort4*)wh)[i] = hi;
        ((ushort4*)wl)[i] = lo;
    }
}

// ---------------- Kernel A (MFMA): fwd GEMM + IF update -------------------
// Block 128 thr = 2 waves, tile 16b x 64h (wave: 16b x 32h). Grid 512 blocks
// (2/CU, 4 waves/CU). Register-prefetch pipeline, XCD-chunked swizzle.
#define PADS 72
__global__ __launch_bounds__(128) void stdp_fwd_mfma(
    const ushort* __restrict__ xh_g,   // [B,D] bf16 (time slice)
    const ushort* __restrict__ xl_g,
    const ushort* __restrict__ wh_g,   // [H,D] bf16
    const ushort* __restrict__ wl_g,
    float* __restrict__ vT,            // [H,B]
    ushort* __restrict__ sT,           // [H,B] bf16
    float* __restrict__ trT)           // [H,B]
{
    __shared__ ushort xhs[16 * PADS];
    __shared__ ushort xls[16 * PADS];
    __shared__ ushort whs[64 * PADS];
    __shared__ ushort wls[64 * PADS];

    const int tid  = threadIdx.x;
    const int lane = tid & 63;
    const int wid  = tid >> 6;            // 0..1: h-half (32h each)

    // XCD-chunked swizzle: XCD k owns 4 contiguous h-tiles x all 16 b-tiles.
    const int flat = blockIdx.y * gridDim.x + blockIdx.x;   // 0..511
    const int xcd  = flat & 7;
    const int c    = flat >> 3;                              // 0..63
    const int h0   = (xcd * 4 + (c >> 4)) * 64;
    const int b0   = (c & 15) * 16;

    const f32x4 z4 = {0.f, 0.f, 0.f, 0.f};
    f32x4 acc[2] = {z4, z4};              // two 16x16 h-tiles

    short8v pxh, pxl, pwh[4], pwl[4];

    auto LOADR = [&](int kn) {
        {
            int r = tid >> 3, g = (tid & 7) * 8;
            pxh = *(const short8v*)&xh_g[(size_t)(b0 + r) * DIM + kn + g];
            pxl = *(const short8v*)&xl_g[(size_t)(b0 + r) * DIM + kn + g];
        }
#pragma unroll
        for (int p = 0; p < 4; ++p) {
            int i = p * 128 + tid;
            int r = i >> 3, g = (i & 7) * 8;
            pwh[p] = *(const short8v*)&wh_g[(size_t)(h0 + r) * DIM + kn + g];
            pwl[p] = *(const short8v*)&wl_g[(size_t)(h0 + r) * DIM + kn + g];
        }
    };
    auto WRITE = [&]() {
        {
            int r = tid >> 3, g = (tid & 7) * 8;
            *(short8v*)&xhs[r * PADS + g] = pxh;
            *(short8v*)&xls[r * PADS + g] = pxl;
        }
#pragma unroll
        for (int p = 0; p < 4; ++p) {
            int i = p * 128 + tid;
            int r = i >> 3, g = (i & 7) * 8;
            *(short8v*)&whs[r * PADS + g] = pwh[p];
            *(short8v*)&wls[r * PADS + g] = pwl[p];
        }
    };

    LOADR(0);
    WRITE();
    __syncthreads();

    for (int k0 = 0; k0 < DIM; k0 += 64) {
        const bool more = (k0 + 64 < DIM);
        if (more) LOADR(k0 + 64);

#pragma unroll
        for (int kk = 0; kk < 2; ++kk) {
            const int kloc = kk * 32 + (lane >> 4) * 8;
            const int fr   = lane & 15;
            short8v axh = *(const short8v*)&xhs[fr * PADS + kloc];
            short8v axl = *(const short8v*)&xls[fr * PADS + kloc];
            const int hb = wid * 32 + fr;
            short8v bh0 = *(const short8v*)&whs[hb * PADS + kloc];
            short8v bh1 = *(const short8v*)&whs[(hb + 16) * PADS + kloc];
            short8v bl0 = *(const short8v*)&wls[hb * PADS + kloc];
            short8v bl1 = *(const short8v*)&wls[(hb + 16) * PADS + kloc];

            acc[0] = __builtin_amdgcn_mfma_f32_16x16x32_bf16(axh, bh0, acc[0], 0, 0, 0);
            acc[0] = __builtin_amdgcn_mfma_f32_16x16x32_bf16(axh, bl0, acc[0], 0, 0, 0);
            acc[0] = __builtin_amdgcn_mfma_f32_16x16x32_bf16(axl, bh0, acc[0], 0, 0, 0);
            acc[1] = __builtin_amdgcn_mfma_f32_16x16x32_bf16(axh, bh1, acc[1], 0, 0, 0);
            acc[1] = __builtin_amdgcn_mfma_f32_16x16x32_bf16(axh, bl1, acc[1], 0, 0, 0);
            acc[1] = __builtin_amdgcn_mfma_f32_16x16x32_bf16(axl, bh1, acc[1], 0, 0, 0);
        }

        if (more) {
            __syncthreads();   // all waves done reading this K-tile
            WRITE();           // write prefetched next K-tile
            __syncthreads();
        }
    }

    // fused IF update, [H,B] layout -> float4 RMW per fragment.
    // C/D layout: col(b)=lane&15? NO: A rows = b, so D row=b... here A=x (rows b),
    // B=w (rows h): D[row=b][col=h], row=(lane>>4)*4+j, col=lane&15.
#pragma unroll
    for (int n = 0; n < 2; ++n) {
        const int h = h0 + wid * 32 + n * 16 + (lane & 15);
        const int b = b0 + (lane >> 4) * 4;
        const size_t base = (size_t)h * BATCH + b;
        float4 vv = *(float4*)&vT[base];
        float4 tr = *(float4*)&trT[base];
        ushort4 sq;
        float* vp = &vv.x;
        float* tp = &tr.x;
        ushort* sp = &sq.x;
#pragma unroll
        for (int j = 0; j < 4; ++j) {
            float nv = vp[j] + acc[n][j];
            float s  = (nv >= 1.0f) ? 1.0f : 0.0f;
            vp[j] = (nv >= 1.0f) ? 0.0f : nv;
            tp[j] += s;
            sp[j] = f32_to_bf16u(s);
        }
        *(float4*)&vT[base]  = vv;
        *(float4*)&trT[base] = tr;
        *(ushort4*)&sT[base] = sq;
    }
}

// ---------------- Kernel B (MFMA): W += c * sT @ xT^T, emit splits --------
// dw[h,d] = sum_b sT[h,b]*xT[d,b]. Single-wave blocks, tile 32h x 64d,
// grid 1024 blocks (4/CU). All operands L2-resident; direct-to-reg.
__global__ __launch_bounds__(64) void stdp_wupd_mfma(
    const ushort* __restrict__ sT,    // [H,B] bf16 (exact 0/1)
    const ushort* __restrict__ xTh,   // [D,B] bf16 (time slice)
    const ushort* __restrict__ xTl,
    float* __restrict__ w,            // [H,D] fp32 master
    ushort* __restrict__ wh,
    ushort* __restrict__ wl)
{
    const int lane = threadIdx.x;
    const int flat = blockIdx.y * gridDim.x + blockIdx.x;   // gx=16, 0..1023
    const int xcd  = flat & 7;
    const int c    = flat >> 3;                              // 0..127
    const int h0   = (xcd * 8 + (c >> 4)) * 32;
    const int d0   = (c & 15) * 64;

    const int fr = lane & 15;
    const int kg = (lane >> 4) * 8;

    const f32x4 z4 = {0.f, 0.f, 0.f, 0.f};
    f32x4 acc[2][4] = {{z4, z4, z4, z4}, {z4, z4, z4, z4}};

#pragma unroll 2
    for (int b0 = 0; b0 < BATCH; b0 += 32) {
        short8v a0 = *(const short8v*)&sT[(size_t)(h0 + fr) * BATCH + b0 + kg];
        short8v a1 = *(const short8v*)&sT[(size_t)(h0 + 16 + fr) * BATCH + b0 + kg];
#pragma unroll
        for (int n = 0; n < 4; ++n) {
            short8v bh = *(const short8v*)&xTh[(size_t)(d0 + n * 16 + fr) * BATCH + b0 + kg];
            short8v bl = *(const short8v*)&xTl[(size_t)(d0 + n * 16 + fr) * BATCH + b0 + kg];
            acc[0][n] = __builtin_amdgcn_mfma_f32_16x16x32_bf16(a0, bh, acc[0][n], 0, 0, 0);
            acc[0][n] = __builtin_amdgcn_mfma_f32_16x16x32_bf16(a0, bl, acc[0][n], 0, 0, 0);
            acc[1][n] = __builtin_amdgcn_mfma_f32_16x16x32_bf16(a1, bh, acc[1][n], 0, 0, 0);
            acc[1][n] = __builtin_amdgcn_mfma_f32_16x16x32_bf16(a1, bl, acc[1][n], 0, 0, 0);
        }
    }

    // D[row=h][col=d]: row=(lane>>4)*4+j, col=lane&15.
#pragma unroll
    for (int m = 0; m < 2; ++m) {
#pragma unroll
        for (int n = 0; n < 4; ++n) {
            const int h = h0 + m * 16 + (lane >> 4) * 4;
            const int d = d0 + n * 16 + fr;
#pragma unroll
            for (int j = 0; j < 4; ++j) {
                size_t idx = (size_t)(h + j) * DIM + d;
                float wv = fmaf(LR_OVER_B, acc[m][n][j], w[idx]);
                w[idx] = wv;
                ushort hb = f32_to_bf16u(wv);
                wh[idx] = hb;
                wl[idx] = f32_to_bf16u(wv - bf16u_to_f32(hb));
            }
        }
    }
}

// ---------------- final: d_out[b,h] = trT[h,b] ----------------------------
__global__ __launch_bounds__(256) void transpose_out(
    const float* __restrict__ trT, float* __restrict__ out)
{
    __shared__ float tile[32][33];
    const int h0 = blockIdx.x * 32;
    const int b0 = blockIdx.y * 32;
    const int tx = threadIdx.x & 31;
    const int ty = threadIdx.x >> 5;
#pragma unroll
    for (int r = 0; r < 32; r += 8)
        tile[ty + r][tx] = trT[(size_t)(h0 + ty + r) * BATCH + b0 + tx];
    __syncthreads();
#pragma unroll
    for (int r = 0; r < 32; r += 8)
        out[(size_t)(b0 + ty + r) * HID + h0 + tx] = tile[tx][ty + r];
}

// ---------------- fallback fp32 kernels (round-0) -------------------------
#define BK 16
__global__ __launch_bounds__(256) void stdp_fwd_if(
    const float* __restrict__ x, const float* __restrict__ w,
    float* __restrict__ v, float* __restrict__ s, float* __restrict__ trace)
{
    __shared__ float as[BK][64];
    __shared__ float bs[BK][64];
    const int tid = threadIdx.x;
    const int tx = tid & 15, ty = tid >> 4;
    const int b0 = blockIdx.y * 64, h0 = blockIdx.x * 64;
    const int row = tid >> 2, kq = (tid & 3) * 4;
    float acc[4][4] = {};
    for (int k0 = 0; k0 < DIM; k0 += BK) {
        float4 ga = *(const float4*)&x[(size_t)(b0 + row) * DIM + k0 + kq];
        float4 gb = *(const float4*)&w[(size_t)(h0 + row) * DIM + k0 + kq];
        __syncthreads();
        as[kq + 0][row] = ga.x; as[kq + 1][row] = ga.y;
        as[kq + 2][row] = ga.z; as[kq + 3][row] = ga.w;
        bs[kq + 0][row] = gb.x; bs[kq + 1][row] = gb.y;
        bs[kq + 2][row] = gb.z; bs[kq + 3][row] = gb.w;
        __syncthreads();
#pragma unroll
        for (int kk = 0; kk < BK; ++kk) {
            float4 af = *(const float4*)&as[kk][ty * 4];
            float4 bf = *(const float4*)&bs[kk][tx * 4];
            float av[4] = {af.x, af.y, af.z, af.w};
            float bv[4] = {bf.x, bf.y, bf.z, bf.w};
#pragma unroll
            for (int m = 0; m < 4; ++m)
#pragma unroll
                for (int n = 0; n < 4; ++n)
                    acc[m][n] = fmaf(av[m], bv[n], acc[m][n]);
        }
    }
#pragma unroll
    for (int m = 0; m < 4; ++m) {
        size_t idx = (size_t)(b0 + ty * 4 + m) * HID + h0 + tx * 4;
        float4 vv = *(float4*)&v[idx];
        float4 tr = *(float4*)&trace[idx];
        float4 sv;
        float* vvp = &vv.x; float* trp = &tr.x; float* svp = &sv.x;
#pragma unroll
        for (int n = 0; n < 4; ++n) {
            float nv = vvp[n] + acc[m][n];
            float sp = (nv >= 1.0f) ? 1.0f : 0.0f;
            vvp[n] = (nv >= 1.0f) ? 0.0f : nv;
            svp[n] = sp; trp[n] += sp;
        }
        *(float4*)&v[idx] = vv;
        *(float4*)&s[idx] = sv;
        *(float4*)&trace[idx] = tr;
    }
}

__global__ __launch_bounds__(256) void stdp_wupd(
    const float* __restrict__ x, const float* __restrict__ s,
    float* __restrict__ w)
{
    __shared__ float ss[BK][64];
    __shared__ float xs[BK][64];
    const int tid = threadIdx.x;
    const int tx = tid & 15, ty = tid >> 4;
    const int h0 = blockIdx.y * 64, d0 = blockIdx.x * 64;
    const int krow = tid >> 4, c4 = (tid & 15) * 4;
    float acc[4][4] = {};
    for (int bk0 = 0; bk0 < BATCH; bk0 += BK) {
        float4 gs = *(const float4*)&s[(size_t)(bk0 + krow) * HID + h0 + c4];
        float4 gx = *(const float4*)&x[(size_t)(bk0 + krow) * DIM + d0 + c4];
        __syncthreads();
        *(float4*)&ss[krow][c4] = gs;
        *(float4*)&xs[krow][c4] = gx;
        __syncthreads();
#pragma unroll
        for (int kk = 0; kk < BK; ++kk) {
            float4 af = *(const float4*)&ss[kk][ty * 4];
            float4 bf = *(const float4*)&xs[kk][tx * 4];
            float av[4] = {af.x, af.y, af.z, af.w};
            float bv[4] = {bf.x, bf.y, bf.z, bf.w};
#pragma unroll
            for (int m = 0; m < 4; ++m)
#pragma unroll
                for (int n = 0; n < 4; ++n)
                    acc[m][n] = fmaf(av[m], bv[n], acc[m][n]);
        }
    }
#pragma unroll
    for (int m = 0; m < 4; ++m) {
        size_t idx = (size_t)(h0 + ty * 4 + m) * DIM + d0 + tx * 4;
        float4 wv = *(float4*)&w[idx];
        wv.x = fmaf(LR_OVER_B, acc[m][0], wv.x);
        wv.y = fmaf(LR_OVER_B, acc[m][1], wv.y);
        wv.z = fmaf(LR_OVER_B, acc[m][2], wv.z);
        wv.w = fmaf(LR_OVER_B, acc[m][3], wv.w);
        *(float4*)&w[idx] = wv;
    }
}

extern "C" void kernel_launch(void* const* d_in, const int* in_sizes, int n_in,
                              void* d_out, int out_size, void* d_ws, size_t ws_size,
                              hipStream_t stream) {
    (void)in_sizes; (void)n_in;
    const float* x_seq  = (const float*)d_in[0];   // [T, B, D]
    const float* weight = (const float*)d_in[1];   // [H, D]
    float* out = (float*)d_out;                    // [B, H]

    const size_t WN = (size_t)HID * DIM;              // 2097152
    const size_t BH = (size_t)BATCH * HID;            // 524288
    const size_t XN = (size_t)T_STEPS * BATCH * DIM;  // 13107200

    // fast path ws: W | vT | trT | Wh | Wl | sT | xh | xl | xTh | xTl
    const size_t need = 4 * (WN + 2 * BH) + 2 * (2 * WN + BH + 4 * XN);

    if (ws_size >= need) {
        float*  W   = (float*)d_ws;
        float*  vT  = W + WN;
        float*  trT = vT + BH;
        ushort* Wh  = (ushort*)(trT + BH);
        ushort* Wl  = Wh + WN;
        ushort* sT  = Wl + WN;
        ushort* xh  = sT + BH;
        ushort* xl  = xh + XN;
        ushort* xTh = xl + XN;
        ushort* xTl = xTh + XN;

        split_x_kernel<<<2048, 256, 0, stream>>>(x_seq, xh, xl, (long)(XN / 4));
        transpose_split_x<<<dim3(DIM / 32, BATCH / 32, T_STEPS), 256, 0, stream>>>(
            x_seq, xTh, xTl);
        split_w_kernel<<<1024, 256, 0, stream>>>(weight, W, Wh, Wl, (long)(WN / 4));
        hipMemsetAsync(vT, 0, BH * 4, stream);
        hipMemsetAsync(trT, 0, BH * 4, stream);

        dim3 blkA(128), grdA(32, 16);   // 512 blocks: 32 h-tiles x 16 b-tiles
        dim3 blkB(64),  grdB(16, 64);   // 1024 blocks: 16 d-tiles x 64 h-tiles

        for (int t = 0; t < T_STEPS; ++t) {
            const ushort* xht = xh + (size_t)t * BATCH * DIM;
            const ushort* xlt = xl + (size_t)t * BATCH * DIM;
            stdp_fwd_mfma<<<grdA, blkA, 0, stream>>>(xht, xlt, Wh, Wl, vT, sT, trT);
            if (t < T_STEPS - 1) {
                const ushort* xTht = xTh + (size_t)t * DIM * BATCH;
                const ushort* xTlt = xTl + (size_t)t * DIM * BATCH;
                stdp_wupd_mfma<<<grdB, blkB, 0, stream>>>(sT, xTht, xTlt, W, Wh, Wl);
            }
        }
        transpose_out<<<dim3(HID / 32, BATCH / 32), 256, 0, stream>>>(trT, out);
    } else {
        // fallback: fp32 VALU path (needs ~12.6 MB)
        float* w = (float*)d_ws;
        float* v = w + WN;
        float* s = v + BH;
        hipMemcpyAsync(w, weight, WN * 4, hipMemcpyDeviceToDevice, stream);
        hipMemsetAsync(v, 0, BH * 4, stream);
        hipMemsetAsync(out, 0, (size_t)out_size * 4, stream);
        dim3 blkA(256), grdA(HID / 64, BATCH / 64);
        dim3 blkB(256), grdB(DIM / 64, HID / 64);
        for (int t = 0; t < T_STEPS; ++t) {
            const float* xt = x_seq + (size_t)t * BATCH * DIM;
            stdp_fwd_if<<<grdA, blkA, 0, stream>>>(xt, w, v, s, out);
            if (t < T_STEPS - 1) {
                stdp_wupd<<<grdB, blkB, 0, stream>>>(xt, s, w);
            }
        }
    }
}